// Round 8
// baseline (877.071 us; speedup 1.0000x reference)
//
// Round 8: (1) MFMA shape 16x16x32 -> 32x32x16 (2382 vs 2075 TF ceiling; 24
// MFMAs/t instead of 48, same staging); (2) JCHUNKS 8->20 to shrink the
// dispatch tail (6.1 -> 15.3 block generations). Pipeline = round-5/7 verified
// structure. C/D layout: col=lane&31, row=(reg&3)+8*(reg>>2)+4*(lane>>5).
#include <hip/hip_runtime.h>
#include <cstdint>
#include <cstddef>

#define K_DIM 512
#define BM 128
#define BN 128
#define BK 32
#define JCHUNKS 20

typedef __attribute__((ext_vector_type(8))) __bf16 bf16x8;
typedef __attribute__((ext_vector_type(8))) short short8;
typedef __attribute__((ext_vector_type(4))) float f32x4;
typedef __attribute__((ext_vector_type(16))) float f32x16;

__device__ __forceinline__ ushort bf16_rn(float x) {
    uint u = __float_as_uint(x);
    return (ushort)((u + 0x7fffu + ((u >> 16) & 1u)) >> 16);
}

// ---------------------------------------------------------------------------
// Kernel 0: row norms of A and B (padded), init vmin[] = +inf, pad nb = +inf.
// ---------------------------------------------------------------------------
__global__ __launch_bounds__(256) void norms_init_kernel(
    const float* __restrict__ A, const float* __restrict__ B,
    float* __restrict__ na, float* __restrict__ nb,
    unsigned* __restrict__ vmin, int N, int M, int Npad, int Mpad)
{
    int w = (int)((blockIdx.x * blockDim.x + threadIdx.x) >> 6);
    int lane = threadIdx.x & 63;
    if (w >= Npad + Mpad) return;
    if (w < Npad) {
        float s = 0.f;
        if (w < N) {
            const float* src = A + (size_t)w * K_DIM + lane * 8;
            float4 v0 = *(const float4*)src;
            float4 v1 = *(const float4*)(src + 4);
            s = v0.x*v0.x + v0.y*v0.y + v0.z*v0.z + v0.w*v0.w
              + v1.x*v1.x + v1.y*v1.y + v1.z*v1.z + v1.w*v1.w;
            #pragma unroll
            for (int m = 1; m < 64; m <<= 1) s += __shfl_xor(s, m, 64);
        }
        if (lane == 0) { na[w] = s; vmin[w] = 0x7f800000u; }
    } else {
        int j = w - Npad;
        float s = __builtin_inff();   // padded centers never win the min
        if (j < M) {
            const float* src = B + (size_t)j * K_DIM + lane * 8;
            float4 v0 = *(const float4*)src;
            float4 v1 = *(const float4*)(src + 4);
            s = v0.x*v0.x + v0.y*v0.y + v0.z*v0.z + v0.w*v0.w
              + v1.x*v1.x + v1.y*v1.y + v1.z*v1.z + v1.w*v1.w;
            #pragma unroll
            for (int m = 1; m < 64; m <<= 1) s += __shfl_xor(s, m, 64);
        }
        if (lane == 0) nb[j] = s;
    }
}

// ---------------------------------------------------------------------------
// Kernel 1: preconvert fp32 -> bf16 hi/lo in the per-(tile,kt) LDS image
// layout [tile][kt][g][m][8] so the GEMM can global_load_lds it linearly.
// ---------------------------------------------------------------------------
__global__ __launch_bounds__(256) void preconvert_kernel(
    const float* __restrict__ src, ushort* __restrict__ hiW, ushort* __restrict__ loW,
    int realRows, int padRows)
{
    int c = blockIdx.x * 256 + threadIdx.x;            // chunk id
    int total = padRows * (K_DIM / 8);
    if (c >= total) return;
    int m    = c & (BM - 1);
    int g    = (c >> 7) & 3;
    int kt   = (c >> 9) & 15;
    int tile = c >> 13;
    int row  = tile * BM + m;
    int k    = kt * BK + g * 8;
    float f[8];
    if (row < realRows) {
        float4 x0 = *(const float4*)(src + (size_t)row * K_DIM + k);
        float4 x1 = *(const float4*)(src + (size_t)row * K_DIM + k + 4);
        f[0]=x0.x; f[1]=x0.y; f[2]=x0.z; f[3]=x0.w;
        f[4]=x1.x; f[5]=x1.y; f[6]=x1.z; f[7]=x1.w;
    } else {
        #pragma unroll
        for (int q = 0; q < 8; ++q) f[q] = 0.f;
    }
    short8 hv, lv;
    #pragma unroll
    for (int q = 0; q < 8; ++q) {
        ushort hb = bf16_rn(f[q]);
        float  lo = f[q] - __uint_as_float((uint)hb << 16);
        hv[q] = (short)hb;
        lv[q] = (short)bf16_rn(lo);
    }
    *(short8*)(hiW + (size_t)c * 8) = hv;
    *(short8*)(loW + (size_t)c * 8) = lv;
}

// ---------------------------------------------------------------------------
// Kernel 2: MFMA GEMM + fused row-min, 32x32x16 bf16, double-buffered
// 2-phase pipeline. 4 waves (2x2), wave tile 64x64 = 2x2 frags of 32x32.
// 3 MFMA per fragment pair (ah*bh + ah*bl + al*bh) x 2 k-steps = 24 MFMA/t.
// ---------------------------------------------------------------------------
__global__ __launch_bounds__(256, 2) void gemm_min_pre(
    const ushort* __restrict__ AhiW, const ushort* __restrict__ AloW,
    const ushort* __restrict__ BhiW, const ushort* __restrict__ BloW,
    const float* __restrict__ na, const float* __restrict__ nb,
    unsigned* __restrict__ vmin, int N, int njt)
{
    __shared__ ushort Ah[2][4096], Al[2][4096], Bh[2][4096], Bl[2][4096]; // 64 KB

    const int tid  = threadIdx.x;
    const int lane = tid & 63;
    const int wave = tid >> 6;
    const int wr = (wave >> 1) * 64;
    const int wc = (wave & 1) * 64;
    const int lr = lane & 31;     // row within a 32-row fragment
    const int lh = lane >> 5;     // k-subgroup select (8 elems each)
    const int tile = blockIdx.y;  // A-tile (slow axis)

    const int per = (njt + JCHUNKS - 1) / JCHUNKS;
    const int jt_begin = min((int)blockIdx.x * per, njt);   // chunk = fast axis
    const int jt_end   = min(jt_begin + per, njt);

    float localmin[32];
    #pragma unroll
    for (int u = 0; u < 32; ++u) localmin[u] = __builtin_inff();

    auto STAGE = [&](int buf, int t) {
        const int jt = jt_begin + (t >> 4);
        const int kt = t & 15;
        const ushort* sAh = AhiW + ((size_t)tile * 16 + kt) * 4096;
        const ushort* sAl = AloW + ((size_t)tile * 16 + kt) * 4096;
        const ushort* sBh = BhiW + ((size_t)jt   * 16 + kt) * 4096;
        const ushort* sBl = BloW + ((size_t)jt   * 16 + kt) * 4096;
        #pragma unroll
        for (int q = 0; q < 2; ++q) {
            int gi = (q * 256 + tid) * 8;          // per-lane global offset
            int li = (q * 256 + wave * 64) * 8;    // wave-uniform LDS base
            __builtin_amdgcn_global_load_lds(
                (const __attribute__((address_space(1))) void*)(sAh + gi),
                (__attribute__((address_space(3))) void*)(&Ah[buf][li]), 16, 0, 0);
            __builtin_amdgcn_global_load_lds(
                (const __attribute__((address_space(1))) void*)(sAl + gi),
                (__attribute__((address_space(3))) void*)(&Al[buf][li]), 16, 0, 0);
            __builtin_amdgcn_global_load_lds(
                (const __attribute__((address_space(1))) void*)(sBh + gi),
                (__attribute__((address_space(3))) void*)(&Bh[buf][li]), 16, 0, 0);
            __builtin_amdgcn_global_load_lds(
                (const __attribute__((address_space(1))) void*)(sBl + gi),
                (__attribute__((address_space(3))) void*)(&Bl[buf][li]), 16, 0, 0);
        }
    };

    if (jt_begin < jt_end) {
        const int T = (jt_end - jt_begin) * 16;

        STAGE(0, 0);
        __syncthreads();           // drain prologue loads
        int cur = 0;

        f32x16 acc[2][2];
        #pragma unroll
        for (int fi = 0; fi < 2; ++fi)
            #pragma unroll
            for (int fj = 0; fj < 2; ++fj) acc[fi][fj] = (f32x16)0.f;

        for (int t = 0; t < T; ++t) {
            if (t + 1 < T) STAGE(cur ^ 1, t + 1);   // issue-early prefetch

            // fragment reads: a-row = wr + fi*32 + lr, k-group = ks*2 + lh
            bf16x8 a_h[2][2], a_l[2][2], b_h[2][2], b_l[2][2];
            #pragma unroll
            for (int fi = 0; fi < 2; ++fi)
                #pragma unroll
                for (int ks = 0; ks < 2; ++ks) {
                    int ra = ((ks * 2 + lh) * 128 + wr + fi * 32 + lr) * 8;
                    a_h[fi][ks] = *(const bf16x8*)(&Ah[cur][ra]);
                    a_l[fi][ks] = *(const bf16x8*)(&Al[cur][ra]);
                }
            #pragma unroll
            for (int fj = 0; fj < 2; ++fj)
                #pragma unroll
                for (int ks = 0; ks < 2; ++ks) {
                    int rb = ((ks * 2 + lh) * 128 + wc + fj * 32 + lr) * 8;
                    b_h[fj][ks] = *(const bf16x8*)(&Bh[cur][rb]);
                    b_l[fj][ks] = *(const bf16x8*)(&Bl[cur][rb]);
                }
            #pragma unroll
            for (int fi = 0; fi < 2; ++fi)
                #pragma unroll
                for (int fj = 0; fj < 2; ++fj)
                    #pragma unroll
                    for (int ks = 0; ks < 2; ++ks) {
                        acc[fi][fj] = __builtin_amdgcn_mfma_f32_32x32x16_bf16(
                            a_h[fi][ks], b_h[fj][ks], acc[fi][fj], 0, 0, 0);
                        acc[fi][fj] = __builtin_amdgcn_mfma_f32_32x32x16_bf16(
                            a_h[fi][ks], b_l[fj][ks], acc[fi][fj], 0, 0, 0);
                        acc[fi][fj] = __builtin_amdgcn_mfma_f32_32x32x16_bf16(
                            a_l[fi][ks], b_h[fj][ks], acc[fi][fj], 0, 0, 0);
                    }

            if ((t & 15) == 15) {   // end of a jt: fold into per-row min
                const int jt = jt_begin + (t >> 4);
                #pragma unroll
                for (int fj = 0; fj < 2; ++fj) {
                    int j = jt * BN + wc + fj * 32 + lr;   // col = lane&31
                    float nbv = nb[j];                     // padded with +inf
                    #pragma unroll
                    for (int fi = 0; fi < 2; ++fi)
                        #pragma unroll
                        for (int r = 0; r < 16; ++r) {
                            float s = fmaf(-2.f, acc[fi][fj][r], nbv);
                            localmin[fi * 16 + r] = fminf(localmin[fi * 16 + r], s);
                        }
                }
                #pragma unroll
                for (int fi = 0; fi < 2; ++fi)
                    #pragma unroll
                    for (int fj = 0; fj < 2; ++fj) acc[fi][fj] = (f32x16)0.f;
            }

            __syncthreads();       // barrier: drains prefetch vmcnt + lgkm
            cur ^= 1;
        }
    }

    // reduce localmin across the 32 column-lanes of each half (cols = lane&31;
    // masks < 32 keep the lane<32 / lane>=32 halves separate, which hold
    // different row sets: row = (r&3)+8*(r>>2)+4*(lane>>5))
    #pragma unroll
    for (int u = 0; u < 32; ++u) {
        float v = localmin[u];
        #pragma unroll
        for (int m = 1; m < 32; m <<= 1) v = fminf(v, __shfl_xor(v, m, 64));
        localmin[u] = v;
    }
    if (lr == 0) {   // lanes 0 and 32 each own 32 rows
        #pragma unroll
        for (int fi = 0; fi < 2; ++fi)
            #pragma unroll
            for (int r = 0; r < 16; ++r) {
                int i = tile * BM + wr + fi * 32 + (r & 3) + 8 * (r >> 2) + 4 * lh;
                if (i < N) {
                    float v = fmaxf(na[i] + localmin[fi * 16 + r], 0.f);
                    atomicMin(&vmin[i], __float_as_uint(v));
                }
            }
    }
}

// ---------------------------------------------------------------------------
// Kernel 2b: fallback — 16x16x32 path converting fp32->bf16 in staging
// (only if ws too small for preconversion). Correctness path only.
// ---------------------------------------------------------------------------
__global__ __launch_bounds__(256, 2) void gemm_min_fused(
    const float* __restrict__ A, const float* __restrict__ B,
    const float* __restrict__ na, const float* __restrict__ nb,
    unsigned* __restrict__ vmin, int N, int M, int njt)
{
    __shared__ ushort Ah[4096], Al[4096], Bh[4096], Bl[4096];

    const int tid  = threadIdx.x;
    const int lane = tid & 63;
    const int wave = tid >> 6;
    const int wr = (wave >> 1) * 64;
    const int wc = (wave & 1) * 64;
    const int tr = lane & 15;
    const int tg = lane >> 4;
    const int i0 = blockIdx.y * BM;

    const int sm = tid & 127;
    const int sh = tid >> 7;

    const int per = (njt + JCHUNKS - 1) / JCHUNKS;
    const int jt_begin = min((int)blockIdx.x * per, njt);
    const int jt_end   = min(jt_begin + per, njt);

    float localmin[16];
    #pragma unroll
    for (int u = 0; u < 16; ++u) localmin[u] = __builtin_inff();

    for (int jt = jt_begin; jt < jt_end; ++jt) {
        const int j0 = jt * BN;
        f32x4 acc[4][4];
        #pragma unroll
        for (int fi = 0; fi < 4; ++fi)
            #pragma unroll
            for (int fj = 0; fj < 4; ++fj) acc[fi][fj] = (f32x4)0.f;

        for (int kt = 0; kt < K_DIM / BK; ++kt) {
            const int k0 = kt * BK + sh * 16;
            {
                float f[16];
                int gi = i0 + sm;
                if (gi < N) {
                    const float* p = A + (size_t)gi * K_DIM + k0;
                    #pragma unroll
                    for (int q = 0; q < 4; ++q) {
                        float4 x = *(const float4*)(p + q * 4);
                        f[q*4+0]=x.x; f[q*4+1]=x.y; f[q*4+2]=x.z; f[q*4+3]=x.w;
                    }
                } else {
                    #pragma unroll
                    for (int q = 0; q < 16; ++q) f[q] = 0.f;
                }
                short8 h0, h1, l0, l1;
                #pragma unroll
                for (int q = 0; q < 8; ++q) {
                    uint u = __float_as_uint(f[q]);
                    h0[q] = (short)(u >> 16);
                    float lo = f[q] - __uint_as_float(u & 0xffff0000u);
                    l0[q] = (short)(__float_as_uint(lo) >> 16);
                }
                #pragma unroll
                for (int q = 0; q < 8; ++q) {
                    uint u = __float_as_uint(f[8+q]);
                    h1[q] = (short)(u >> 16);
                    float lo = f[8+q] - __uint_as_float(u & 0xffff0000u);
                    l1[q] = (short)(__float_as_uint(lo) >> 16);
                }
                int g0 = sh * 2;
                *(short8*)(Ah + (g0 * 128 + sm) * 8)       = h0;
                *(short8*)(Ah + ((g0 + 1) * 128 + sm) * 8) = h1;
                *(short8*)(Al + (g0 * 128 + sm) * 8)       = l0;
                *(short8*)(Al + ((g0 + 1) * 128 + sm) * 8) = l1;
            }
            {
                float f[16];
                int gj = j0 + sm;
                if (gj < M) {
                    const float* p = B + (size_t)gj * K_DIM + k0;
                    #pragma unroll
                    for (int q = 0; q < 4; ++q) {
                        float4 x = *(const float4*)(p + q * 4);
                        f[q*4+0]=x.x; f[q*4+1]=x.y; f[q*4+2]=x.z; f[q*4+3]=x.w;
                    }
                } else {
                    #pragma unroll
                    for (int q = 0; q < 16; ++q) f[q] = 0.f;
                }
                short8 h0, h1, l0, l1;
                #pragma unroll
                for (int q = 0; q < 8; ++q) {
                    uint u = __float_as_uint(f[q]);
                    h0[q] = (short)(u >> 16);
                    float lo = f[q] - __uint_as_float(u & 0xffff0000u);
                    l0[q] = (short)(__float_as_uint(lo) >> 16);
                }
                #pragma unroll
                for (int q = 0; q < 8; ++q) {
                    uint u = __float_as_uint(f[8+q]);
                    h1[q] = (short)(u >> 16);
                    float lo = f[8+q] - __uint_as_float(u & 0xffff0000u);
                    l1[q] = (short)(__float_as_uint(lo) >> 16);
                }
                int g0 = sh * 2;
                *(short8*)(Bh + (g0 * 128 + sm) * 8)       = h0;
                *(short8*)(Bh + ((g0 + 1) * 128 + sm) * 8) = h1;
                *(short8*)(Bl + (g0 * 128 + sm) * 8)       = l0;
                *(short8*)(Bl + ((g0 + 1) * 128 + sm) * 8) = l1;
            }
            __syncthreads();

            bf16x8 a_h[4], a_l[4], b_h[4], b_l[4];
            #pragma unroll
            for (int fi = 0; fi < 4; ++fi) {
                int ra = (tg * 128 + wr + fi * 16 + tr) * 8;
                a_h[fi] = *(const bf16x8*)(Ah + ra);
                a_l[fi] = *(const bf16x8*)(Al + ra);
            }
            #pragma unroll
            for (int fj = 0; fj < 4; ++fj) {
                int rb = (tg * 128 + wc + fj * 16 + tr) * 8;
                b_h[fj] = *(const bf16x8*)(Bh + rb);
                b_l[fj] = *(const bf16x8*)(Bl + rb);
            }
            #pragma unroll
            for (int fi = 0; fi < 4; ++fi)
                #pragma unroll
                for (int fj = 0; fj < 4; ++fj) {
                    acc[fi][fj] = __builtin_amdgcn_mfma_f32_16x16x32_bf16(a_h[fi], b_h[fj], acc[fi][fj], 0, 0, 0);
                    acc[fi][fj] = __builtin_amdgcn_mfma_f32_16x16x32_bf16(a_h[fi], b_l[fj], acc[fi][fj], 0, 0, 0);
                    acc[fi][fj] = __builtin_amdgcn_mfma_f32_16x16x32_bf16(a_l[fi], b_h[fj], acc[fi][fj], 0, 0, 0);
                }
            __syncthreads();
        }

        #pragma unroll
        for (int fj = 0; fj < 4; ++fj) {
            int j = j0 + wc + fj * 16 + tr;
            float nbv = nb[j];
            #pragma unroll
            for (int fi = 0; fi < 4; ++fi)
                #pragma unroll
                for (int r = 0; r < 4; ++r) {
                    float s = fmaf(-2.f, acc[fi][fj][r], nbv);
                    localmin[fi * 4 + r] = fminf(localmin[fi * 4 + r], s);
                }
        }
    }

    #pragma unroll
    for (int u = 0; u < 16; ++u) {
        float v = localmin[u];
        #pragma unroll
        for (int m = 1; m < 16; m <<= 1) v = fminf(v, __shfl_xor(v, m, 64));
        localmin[u] = v;
    }
    if (tr == 0) {
        #pragma unroll
        for (int fi = 0; fi < 4; ++fi)
            #pragma unroll
            for (int r = 0; r < 4; ++r) {
                int i = i0 + wr + fi * 16 + tg * 4 + r;
                if (i < N) {
                    float v = fmaxf(na[i] + localmin[fi * 4 + r], 0.f);
                    atomicMin(&vmin[i], __float_as_uint(v));
                }
            }
    }
}

// ---------------------------------------------------------------------------
// Kernel 3: argmax over vmin (uint bits of non-negative floats).
// ---------------------------------------------------------------------------
__global__ __launch_bounds__(1024) void argmax_kernel(
    const unsigned* __restrict__ vmin, float* __restrict__ out, int N)
{
    unsigned long long best = 0ull;
    for (int i = threadIdx.x; i < N; i += 1024) {
        unsigned long long p =
            ((unsigned long long)vmin[i] << 32) | (unsigned)(~i);
        if (p > best) best = p;
    }
    #pragma unroll
    for (int m = 1; m < 64; m <<= 1) {
        unsigned hi = (unsigned)(best >> 32), lo = (unsigned)best;
        unsigned ohi = __shfl_xor(hi, m, 64);
        unsigned olo = __shfl_xor(lo, m, 64);
        unsigned long long o = ((unsigned long long)ohi << 32) | olo;
        if (o > best) best = o;
    }
    __shared__ unsigned long long sb[16];
    int lane = threadIdx.x & 63, w = threadIdx.x >> 6;
    if (lane == 0) sb[w] = best;
    __syncthreads();
    if (threadIdx.x == 0) {
        unsigned long long b = sb[0];
        #pragma unroll
        for (int w2 = 1; w2 < 16; ++w2) if (sb[w2] > b) b = sb[w2];
        unsigned idx = ~(unsigned)(b & 0xFFFFFFFFull);
        float v = __uint_as_float((unsigned)(b >> 32));
        out[0] = (float)idx;
        out[1] = sqrtf(v);
    }
}

// ---------------------------------------------------------------------------
extern "C" void kernel_launch(void* const* d_in, const int* in_sizes, int n_in,
                              void* d_out, int out_size, void* d_ws, size_t ws_size,
                              hipStream_t stream)
{
    const float* A = (const float*)d_in[0];
    const float* B = (const float*)d_in[1];
    const int N = in_sizes[0] / K_DIM;           // 50000
    const int M = in_sizes[1] / K_DIM;           // 5000
    const int ntile = (N + BM - 1) / BM;         // 391
    const int njt   = (M + BN - 1) / BN;         // 40
    const int Npad = ntile * BM, Mpad = njt * BN;

    char* ws = (char*)d_ws;
    float*    na   = (float*)ws;                     // Npad
    float*    nb   = na + Npad;                      // Mpad
    unsigned* vmin = (unsigned*)(nb + Mpad);         // Npad
    size_t off = ((size_t)(Npad + Mpad + Npad) * 4 + 255) & ~(size_t)255;
    size_t sizeA = (size_t)Npad * K_DIM;             // ushorts
    size_t sizeB = (size_t)Mpad * K_DIM;
    ushort* AhiW = (ushort*)(ws + off);
    ushort* AloW = AhiW + sizeA;
    ushort* BhiW = AloW + sizeA;
    ushort* BloW = BhiW + sizeB;
    size_t need = off + 2 * (sizeA + sizeB) * sizeof(ushort);

    float* out = (float*)d_out;

    int waves = Npad + Mpad;
    hipLaunchKernelGGL(norms_init_kernel, dim3((waves + 3) / 4), dim3(256), 0, stream,
                       A, B, na, nb, vmin, N, M, Npad, Mpad);

    if (ws_size >= need) {
        hipLaunchKernelGGL(preconvert_kernel, dim3((Npad * 64 + 255) / 256), dim3(256), 0, stream,
                           A, AhiW, AloW, N, Npad);
        hipLaunchKernelGGL(preconvert_kernel, dim3((Mpad * 64 + 255) / 256), dim3(256), 0, stream,
                           B, BhiW, BloW, M, Mpad);
        // grid: x = j-chunk (fast), y = A-tile (slow)
        hipLaunchKernelGGL(gemm_min_pre, dim3(JCHUNKS, ntile), dim3(256), 0, stream,
                           AhiW, AloW, BhiW, BloW, na, nb, vmin, N, njt);
    } else {
        hipLaunchKernelGGL(gemm_min_fused, dim3(JCHUNKS, ntile), dim3(256), 0, stream,
                           A, B, na, nb, vmin, N, M, njt);
    }

    hipLaunchKernelGGL(argmax_kernel, dim3(1), dim3(1024), 0, stream,
                       vmin, out, N);
}

// Round 9
// 803.459 us; speedup vs baseline: 1.0916x; 1.0916x over previous
//
// Round 9: 256x256 tile, 8 waves (wave tile 64x128), per=1. Same round-5
// two-barrier pipeline + verified 16x16x32 fragment mapping; geometry scaled
// so each barrier amortizes 768 MFMAs (3725 CU-cyc) instead of 192 (931).
// LDS 128KB dbuf -> 1 block/CU (8 waves, same waves/CU as before).
#include <hip/hip_runtime.h>
#include <cstdint>
#include <cstddef>

#define K_DIM 512
#define BM 256
#define BN 256
#define BK 32

typedef __attribute__((ext_vector_type(8))) __bf16 bf16x8;
typedef __attribute__((ext_vector_type(8))) short short8;
typedef __attribute__((ext_vector_type(4))) float f32x4;

__device__ __forceinline__ ushort bf16_rn(float x) {
    uint u = __float_as_uint(x);
    return (ushort)((u + 0x7fffu + ((u >> 16) & 1u)) >> 16);
}

// ---------------------------------------------------------------------------
// Kernel 0: row norms of A and B (padded), init vmin[] = +inf, pad nb = +inf.
// ---------------------------------------------------------------------------
__global__ __launch_bounds__(256) void norms_init_kernel(
    const float* __restrict__ A, const float* __restrict__ B,
    float* __restrict__ na, float* __restrict__ nb,
    unsigned* __restrict__ vmin, int N, int M, int Npad, int Mpad)
{
    int w = (int)((blockIdx.x * blockDim.x + threadIdx.x) >> 6);
    int lane = threadIdx.x & 63;
    if (w >= Npad + Mpad) return;
    if (w < Npad) {
        float s = 0.f;
        if (w < N) {
            const float* src = A + (size_t)w * K_DIM + lane * 8;
            float4 v0 = *(const float4*)src;
            float4 v1 = *(const float4*)(src + 4);
            s = v0.x*v0.x + v0.y*v0.y + v0.z*v0.z + v0.w*v0.w
              + v1.x*v1.x + v1.y*v1.y + v1.z*v1.z + v1.w*v1.w;
            #pragma unroll
            for (int m = 1; m < 64; m <<= 1) s += __shfl_xor(s, m, 64);
        }
        if (lane == 0) { na[w] = s; vmin[w] = 0x7f800000u; }
    } else {
        int j = w - Npad;
        float s = __builtin_inff();   // padded centers never win the min
        if (j < M) {
            const float* src = B + (size_t)j * K_DIM + lane * 8;
            float4 v0 = *(const float4*)src;
            float4 v1 = *(const float4*)(src + 4);
            s = v0.x*v0.x + v0.y*v0.y + v0.z*v0.z + v0.w*v0.w
              + v1.x*v1.x + v1.y*v1.y + v1.z*v1.z + v1.w*v1.w;
            #pragma unroll
            for (int m = 1; m < 64; m <<= 1) s += __shfl_xor(s, m, 64);
        }
        if (lane == 0) nb[j] = s;
    }
}

// ---------------------------------------------------------------------------
// Kernel 1: preconvert fp32 -> bf16 hi/lo in the per-(tile256,kt) LDS image
// layout [tile][kt][g][m][8] (m = 0..255) so the GEMM global_load_lds's it
// linearly. One thread per 8-elem chunk; output-coalesced.
// ---------------------------------------------------------------------------
__global__ __launch_bounds__(256) void preconvert_kernel(
    const float* __restrict__ src, ushort* __restrict__ hiW, ushort* __restrict__ loW,
    int realRows, int padRows)
{
    int c = blockIdx.x * 256 + threadIdx.x;            // chunk id
    int total = padRows * (K_DIM / 8);
    if (c >= total) return;
    int m    = c & 255;
    int g    = (c >> 8) & 3;
    int kt   = (c >> 10) & 15;
    int tile = c >> 14;
    int row  = tile * 256 + m;
    int k    = kt * BK + g * 8;
    float f[8];
    if (row < realRows) {
        float4 x0 = *(const float4*)(src + (size_t)row * K_DIM + k);
        float4 x1 = *(const float4*)(src + (size_t)row * K_DIM + k + 4);
        f[0]=x0.x; f[1]=x0.y; f[2]=x0.z; f[3]=x0.w;
        f[4]=x1.x; f[5]=x1.y; f[6]=x1.z; f[7]=x1.w;
    } else {
        #pragma unroll
        for (int q = 0; q < 8; ++q) f[q] = 0.f;
    }
    short8 hv, lv;
    #pragma unroll
    for (int q = 0; q < 8; ++q) {
        ushort hb = bf16_rn(f[q]);
        float  lo = f[q] - __uint_as_float((uint)hb << 16);
        hv[q] = (short)hb;
        lv[q] = (short)bf16_rn(lo);
    }
    *(short8*)(hiW + (size_t)c * 8) = hv;
    *(short8*)(loW + (size_t)c * 8) = lv;
}

// ---------------------------------------------------------------------------
// Kernel 2: MFMA GEMM + fused row-min, 256x256 tile, 8 waves (2M x 2N grid of
// 64x128 wave tiles), 16x16x32 bf16, 3 MFMA per frag pair, double-buffered
// issue-early pipeline (round-5 structure). One j-tile per block (per=1).
// ---------------------------------------------------------------------------
__global__ __launch_bounds__(512, 1) void gemm_min_pre(
    const ushort* __restrict__ AhiW, const ushort* __restrict__ AloW,
    const ushort* __restrict__ BhiW, const ushort* __restrict__ BloW,
    const float* __restrict__ na, const float* __restrict__ nb,
    unsigned* __restrict__ vmin, int N)
{
    __shared__ ushort Ah[2][8192], Al[2][8192], Bh[2][8192], Bl[2][8192]; // 128 KB

    const int tid  = threadIdx.x;
    const int lane = tid & 63;
    const int wave = tid >> 6;            // 0..7
    const int wr = (wave >> 1) * 64;      // 4 waves along M (rows)
    const int wc = (wave & 1) * 128;      // 2 waves along N (cols)
    const int tr = lane & 15;
    const int tg = lane >> 4;
    const int tile = blockIdx.y;          // A-tile (slow axis)
    const int jt   = blockIdx.x;          // j-tile (fast axis; shares A-tile)

    auto STAGE = [&](int buf, int kt) {
        const ushort* sAh = AhiW + ((size_t)tile * 16 + kt) * 8192;
        const ushort* sAl = AloW + ((size_t)tile * 16 + kt) * 8192;
        const ushort* sBh = BhiW + ((size_t)jt   * 16 + kt) * 8192;
        const ushort* sBl = BloW + ((size_t)jt   * 16 + kt) * 8192;
        #pragma unroll
        for (int q = 0; q < 2; ++q) {
            int gi = (q * 512 + tid) * 8;          // per-lane global offset
            int li = (q * 512 + wave * 64) * 8;    // wave-uniform LDS base
            __builtin_amdgcn_global_load_lds(
                (const __attribute__((address_space(1))) void*)(sAh + gi),
                (__attribute__((address_space(3))) void*)(&Ah[buf][li]), 16, 0, 0);
            __builtin_amdgcn_global_load_lds(
                (const __attribute__((address_space(1))) void*)(sAl + gi),
                (__attribute__((address_space(3))) void*)(&Al[buf][li]), 16, 0, 0);
            __builtin_amdgcn_global_load_lds(
                (const __attribute__((address_space(1))) void*)(sBh + gi),
                (__attribute__((address_space(3))) void*)(&Bh[buf][li]), 16, 0, 0);
            __builtin_amdgcn_global_load_lds(
                (const __attribute__((address_space(1))) void*)(sBl + gi),
                (__attribute__((address_space(3))) void*)(&Bl[buf][li]), 16, 0, 0);
        }
    };

    f32x4 acc[4][8];
    #pragma unroll
    for (int fi = 0; fi < 4; ++fi)
        #pragma unroll
        for (int fj = 0; fj < 8; ++fj) acc[fi][fj] = (f32x4)0.f;

    STAGE(0, 0);
    __syncthreads();           // drain prologue loads
    int cur = 0;

    for (int kt = 0; kt < 16; ++kt) {
        if (kt + 1 < 16) STAGE(cur ^ 1, kt + 1);   // issue-early prefetch

        bf16x8 a_h[4], a_l[4];
        #pragma unroll
        for (int fi = 0; fi < 4; ++fi) {
            int ra = (tg * 256 + wr + fi * 16 + tr) * 8;
            a_h[fi] = *(const bf16x8*)(&Ah[cur][ra]);
            a_l[fi] = *(const bf16x8*)(&Al[cur][ra]);
        }
        #pragma unroll
        for (int fj = 0; fj < 8; ++fj) {
            int rb = (tg * 256 + wc + fj * 16 + tr) * 8;
            bf16x8 b_h = *(const bf16x8*)(&Bh[cur][rb]);
            bf16x8 b_l = *(const bf16x8*)(&Bl[cur][rb]);
            #pragma unroll
            for (int fi = 0; fi < 4; ++fi) {
                acc[fi][fj] = __builtin_amdgcn_mfma_f32_16x16x32_bf16(a_h[fi], b_h, acc[fi][fj], 0, 0, 0);
                acc[fi][fj] = __builtin_amdgcn_mfma_f32_16x16x32_bf16(a_h[fi], b_l, acc[fi][fj], 0, 0, 0);
                acc[fi][fj] = __builtin_amdgcn_mfma_f32_16x16x32_bf16(a_l[fi], b_h, acc[fi][fj], 0, 0, 0);
            }
        }

        __syncthreads();       // barrier: drains prefetch vmcnt + lgkm
        cur ^= 1;
    }

    // epilogue: fold nb - 2*dot into per-row min, reduce over 16 col-lanes
    float localmin[16];
    #pragma unroll
    for (int u = 0; u < 16; ++u) localmin[u] = __builtin_inff();

    #pragma unroll
    for (int fj = 0; fj < 8; ++fj) {
        int j = jt * BN + wc + fj * 16 + tr;
        float nbv = nb[j];                         // padded with +inf
        #pragma unroll
        for (int fi = 0; fi < 4; ++fi)
            #pragma unroll
            for (int r = 0; r < 4; ++r) {
                float s = fmaf(-2.f, acc[fi][fj][r], nbv);
                localmin[fi * 4 + r] = fminf(localmin[fi * 4 + r], s);
            }
    }

    #pragma unroll
    for (int u = 0; u < 16; ++u) {
        float v = localmin[u];
        #pragma unroll
        for (int m = 1; m < 16; m <<= 1) v = fminf(v, __shfl_xor(v, m, 64));
        localmin[u] = v;
    }
    if (tr == 0) {
        #pragma unroll
        for (int fi = 0; fi < 4; ++fi)
            #pragma unroll
            for (int r = 0; r < 4; ++r) {
                int i = tile * BM + wr + fi * 16 + tg * 4 + r;
                if (i < N) {
                    float v = fmaxf(na[i] + localmin[fi * 4 + r], 0.f);
                    atomicMin(&vmin[i], __float_as_uint(v));
                }
            }
    }
}

// ---------------------------------------------------------------------------
// Kernel 2b: fallback — 128-tile path converting fp32->bf16 in staging
// (only if ws too small for preconversion). Correctness path only.
// ---------------------------------------------------------------------------
__global__ __launch_bounds__(256, 2) void gemm_min_fused(
    const float* __restrict__ A, const float* __restrict__ B,
    const float* __restrict__ na, const float* __restrict__ nb,
    unsigned* __restrict__ vmin, int N, int M, int njt)
{
    __shared__ ushort Ah[4096], Al[4096], Bh[4096], Bl[4096];

    const int tid  = threadIdx.x;
    const int lane = tid & 63;
    const int wave = tid >> 6;
    const int wr = (wave >> 1) * 64;
    const int wc = (wave & 1) * 64;
    const int tr = lane & 15;
    const int tg = lane >> 4;
    const int i0 = blockIdx.y * 128;

    const int sm = tid & 127;
    const int sh = tid >> 7;

    const int per = (njt + 7) / 8;
    const int jt_begin = min((int)blockIdx.x * per, njt);
    const int jt_end   = min(jt_begin + per, njt);

    float localmin[16];
    #pragma unroll
    for (int u = 0; u < 16; ++u) localmin[u] = __builtin_inff();

    for (int jt = jt_begin; jt < jt_end; ++jt) {
        const int j0 = jt * 128;
        f32x4 acc[4][4];
        #pragma unroll
        for (int fi = 0; fi < 4; ++fi)
            #pragma unroll
            for (int fj = 0; fj < 4; ++fj) acc[fi][fj] = (f32x4)0.f;

        for (int kt = 0; kt < K_DIM / BK; ++kt) {
            const int k0 = kt * BK + sh * 16;
            {
                float f[16];
                int gi = i0 + sm;
                if (gi < N) {
                    const float* p = A + (size_t)gi * K_DIM + k0;
                    #pragma unroll
                    for (int q = 0; q < 4; ++q) {
                        float4 x = *(const float4*)(p + q * 4);
                        f[q*4+0]=x.x; f[q*4+1]=x.y; f[q*4+2]=x.z; f[q*4+3]=x.w;
                    }
                } else {
                    #pragma unroll
                    for (int q = 0; q < 16; ++q) f[q] = 0.f;
                }
                short8 h0, h1, l0, l1;
                #pragma unroll
                for (int q = 0; q < 8; ++q) {
                    uint u = __float_as_uint(f[q]);
                    h0[q] = (short)(u >> 16);
                    float lo = f[q] - __uint_as_float(u & 0xffff0000u);
                    l0[q] = (short)(__float_as_uint(lo) >> 16);
                }
                #pragma unroll
                for (int q = 0; q < 8; ++q) {
                    uint u = __float_as_uint(f[8+q]);
                    h1[q] = (short)(u >> 16);
                    float lo = f[8+q] - __uint_as_float(u & 0xffff0000u);
                    l1[q] = (short)(__float_as_uint(lo) >> 16);
                }
                int g0 = sh * 2;
                *(short8*)(Ah + (g0 * 128 + sm) * 8)       = h0;
                *(short8*)(Ah + ((g0 + 1) * 128 + sm) * 8) = h1;
                *(short8*)(Al + (g0 * 128 + sm) * 8)       = l0;
                *(short8*)(Al + ((g0 + 1) * 128 + sm) * 8) = l1;
            }
            {
                float f[16];
                int gj = j0 + sm;
                if (gj < M) {
                    const float* p = B + (size_t)gj * K_DIM + k0;
                    #pragma unroll
                    for (int q = 0; q < 4; ++q) {
                        float4 x = *(const float4*)(p + q * 4);
                        f[q*4+0]=x.x; f[q*4+1]=x.y; f[q*4+2]=x.z; f[q*4+3]=x.w;
                    }
                } else {
                    #pragma unroll
                    for (int q = 0; q < 16; ++q) f[q] = 0.f;
                }
                short8 h0, h1, l0, l1;
                #pragma unroll
                for (int q = 0; q < 8; ++q) {
                    uint u = __float_as_uint(f[q]);
                    h0[q] = (short)(u >> 16);
                    float lo = f[q] - __uint_as_float(u & 0xffff0000u);
                    l0[q] = (short)(__float_as_uint(lo) >> 16);
                }
                #pragma unroll
                for (int q = 0; q < 8; ++q) {
                    uint u = __float_as_uint(f[8+q]);
                    h1[q] = (short)(u >> 16);
                    float lo = f[8+q] - __uint_as_float(u & 0xffff0000u);
                    l1[q] = (short)(__float_as_uint(lo) >> 16);
                }
                int g0 = sh * 2;
                *(short8*)(Bh + (g0 * 128 + sm) * 8)       = h0;
                *(short8*)(Bh + ((g0 + 1) * 128 + sm) * 8) = h1;
                *(short8*)(Bl + (g0 * 128 + sm) * 8)       = l0;
                *(short8*)(Bl + ((g0 + 1) * 128 + sm) * 8) = l1;
            }
            __syncthreads();

            bf16x8 a_h[4], a_l[4], b_h[4], b_l[4];
            #pragma unroll
            for (int fi = 0; fi < 4; ++fi) {
                int ra = (tg * 128 + wr + fi * 16 + tr) * 8;
                a_h[fi] = *(const bf16x8*)(Ah + ra);
                a_l[fi] = *(const bf16x8*)(Al + ra);
            }
            #pragma unroll
            for (int fj = 0; fj < 4; ++fj) {
                int rb = (tg * 128 + wc + fj * 16 + tr) * 8;
                b_h[fj] = *(const bf16x8*)(Bh + rb);
                b_l[fj] = *(const bf16x8*)(Bl + rb);
            }
            #pragma unroll
            for (int fi = 0; fi < 4; ++fi)
                #pragma unroll
                for (int fj = 0; fj < 4; ++fj) {
                    acc[fi][fj] = __builtin_amdgcn_mfma_f32_16x16x32_bf16(a_h[fi], b_h[fj], acc[fi][fj], 0, 0, 0);
                    acc[fi][fj] = __builtin_amdgcn_mfma_f32_16x16x32_bf16(a_h[fi], b_l[fj], acc[fi][fj], 0, 0, 0);
                    acc[fi][fj] = __builtin_amdgcn_mfma_f32_16x16x32_bf16(a_l[fi], b_h[fj], acc[fi][fj], 0, 0, 0);
                }
            __syncthreads();
        }

        #pragma unroll
        for (int fj = 0; fj < 4; ++fj) {
            int j = j0 + wc + fj * 16 + tr;
            float nbv = (j < M) ? nb[j] : __builtin_inff();
            #pragma unroll
            for (int fi = 0; fi < 4; ++fi)
                #pragma unroll
                for (int r = 0; r < 4; ++r) {
                    float s = fmaf(-2.f, acc[fi][fj][r], nbv);
                    localmin[fi * 4 + r] = fminf(localmin[fi * 4 + r], s);
                }
        }
    }

    #pragma unroll
    for (int u = 0; u < 16; ++u) {
        float v = localmin[u];
        #pragma unroll
        for (int m = 1; m < 16; m <<= 1) v = fminf(v, __shfl_xor(v, m, 64));
        localmin[u] = v;
    }
    if (tr == 0) {
        #pragma unroll
        for (int fi = 0; fi < 4; ++fi)
            #pragma unroll
            for (int r = 0; r < 4; ++r) {
                int i = i0 + wr + fi * 16 + tg * 4 + r;
                if (i < N) {
                    float v = fmaxf(na[i] + localmin[fi * 4 + r], 0.f);
                    atomicMin(&vmin[i], __float_as_uint(v));
                }
            }
    }
}

// ---------------------------------------------------------------------------
// Kernel 3: argmax over vmin (uint bits of non-negative floats).
// ---------------------------------------------------------------------------
__global__ __launch_bounds__(1024) void argmax_kernel(
    const unsigned* __restrict__ vmin, float* __restrict__ out, int N)
{
    unsigned long long best = 0ull;
    for (int i = threadIdx.x; i < N; i += 1024) {
        unsigned long long p =
            ((unsigned long long)vmin[i] << 32) | (unsigned)(~i);
        if (p > best) best = p;
    }
    #pragma unroll
    for (int m = 1; m < 64; m <<= 1) {
        unsigned hi = (unsigned)(best >> 32), lo = (unsigned)best;
        unsigned ohi = __shfl_xor(hi, m, 64);
        unsigned olo = __shfl_xor(lo, m, 64);
        unsigned long long o = ((unsigned long long)ohi << 32) | olo;
        if (o > best) best = o;
    }
    __shared__ unsigned long long sb[16];
    int lane = threadIdx.x & 63, w = threadIdx.x >> 6;
    if (lane == 0) sb[w] = best;
    __syncthreads();
    if (threadIdx.x == 0) {
        unsigned long long b = sb[0];
        #pragma unroll
        for (int w2 = 1; w2 < 16; ++w2) if (sb[w2] > b) b = sb[w2];
        unsigned idx = ~(unsigned)(b & 0xFFFFFFFFull);
        float v = __uint_as_float((unsigned)(b >> 32));
        out[0] = (float)idx;
        out[1] = sqrtf(v);
    }
}

// ---------------------------------------------------------------------------
extern "C" void kernel_launch(void* const* d_in, const int* in_sizes, int n_in,
                              void* d_out, int out_size, void* d_ws, size_t ws_size,
                              hipStream_t stream)
{
    const float* A = (const float*)d_in[0];
    const float* B = (const float*)d_in[1];
    const int N = in_sizes[0] / K_DIM;           // 50000
    const int M = in_sizes[1] / K_DIM;           // 5000
    const int ntile = (N + BM - 1) / BM;         // 196
    const int njt   = (M + BN - 1) / BN;         // 20
    const int Npad = ntile * BM, Mpad = njt * BN;

    char* ws = (char*)d_ws;
    float*    na   = (float*)ws;                     // Npad
    float*    nb   = na + Npad;                      // Mpad
    unsigned* vmin = (unsigned*)(nb + Mpad);         // Npad
    size_t off = ((size_t)(Npad + Mpad + Npad) * 4 + 255) & ~(size_t)255;
    size_t sizeA = (size_t)Npad * K_DIM;             // ushorts
    size_t sizeB = (size_t)Mpad * K_DIM;
    ushort* AhiW = (ushort*)(ws + off);
    ushort* AloW = AhiW + sizeA;
    ushort* BhiW = AloW + sizeA;
    ushort* BloW = BhiW + sizeB;
    size_t need = off + 2 * (sizeA + sizeB) * sizeof(ushort);

    float* out = (float*)d_out;

    int waves = Npad + Mpad;
    hipLaunchKernelGGL(norms_init_kernel, dim3((waves + 3) / 4), dim3(256), 0, stream,
                       A, B, na, nb, vmin, N, M, Npad, Mpad);

    if (ws_size >= need) {
        hipLaunchKernelGGL(preconvert_kernel, dim3((Npad * 64 + 255) / 256), dim3(256), 0, stream,
                           A, AhiW, AloW, N, Npad);
        hipLaunchKernelGGL(preconvert_kernel, dim3((Mpad * 64 + 255) / 256), dim3(256), 0, stream,
                           B, BhiW, BloW, M, Mpad);
        // grid: x = j-tile (fast; 20 blocks share each A-tile), y = A-tile
        hipLaunchKernelGGL(gemm_min_pre, dim3(njt, ntile), dim3(512), 0, stream,
                           AhiW, AloW, BhiW, BloW, na, nb, vmin, N);
    } else {
        const int ntile128 = (N + 127) / 128;
        const int njt128   = (M + 127) / 128;
        hipLaunchKernelGGL(gemm_min_fused, dim3(8, ntile128), dim3(256), 0, stream,
                           A, B, na, nb, vmin, N, M, njt128);
    }

    hipLaunchKernelGGL(argmax_kernel, dim3(1), dim3(1024), 0, stream,
                       vmin, out, N);
}